// Round 12
// baseline (194.355 us; speedup 1.0000x reference)
//
#include <hip/hip_runtime.h>
#include <hip/hip_bf16.h>

#define B_N 4096
#define L_K 128
#define NTASK 16384          // gram tasks: 256 strips x 64 col-tiles
#define LOSS_BLOCKS 2048
#define LOSS_THREADS 524288  // 2048*256, exactly 8 quads per thread

typedef __bf16 bf16x8 __attribute__((ext_vector_type(8)));
typedef float  f32x4  __attribute__((ext_vector_type(4)));

// ---------------------------------------------------------------------------
// prep: labels f32 -> bf16 (ws), and inv[i] = 1/sqrt(||labels_i||^2 + 128)
// ---------------------------------------------------------------------------
__global__ __launch_bounds__(256) void prep_kernel(const float* __restrict__ labels,
                                                   unsigned short* __restrict__ lb,
                                                   float* __restrict__ inv) {
    const int wave = blockIdx.x * 4 + (threadIdx.x >> 6);
    const int lane = threadIdx.x & 63;
    const int row  = wave;

    const float x0 = labels[row * L_K + lane];
    const float x1 = labels[row * L_K + 64 + lane];

    __hip_bfloat16 h0 = __float2bfloat16(x0);
    __hip_bfloat16 h1 = __float2bfloat16(x1);
    lb[row * L_K + lane]      = *reinterpret_cast<unsigned short*>(&h0);
    lb[row * L_K + 64 + lane] = *reinterpret_cast<unsigned short*>(&h1);

    float s = x0 * x0 + x1 * x1;
    #pragma unroll
    for (int m = 32; m >= 1; m >>= 1) s += __shfl_xor(s, m);
    if (lane == 0) inv[row] = 1.0f / sqrtf(s + 128.0f);
}

// ---------------------------------------------------------------------------
// A: gram -> m8. One wave = one 16x64 tile (r8's validated structure, minus
// o-traffic). m = floor((dot+128)*invi*invj) in {-1,0,1}; stored as uint8
// m+1 in {0,1,2} (exact). LDS transpose (stride 68) gives each lane 4
// consecutive cols -> pack 4 bytes -> one dword store per 4-row group.
// Pure L2/MFMA kernel: no HBM reads besides cold lb misses.
// ---------------------------------------------------------------------------
__global__ __launch_bounds__(256) void gram_kernel(const unsigned short* __restrict__ lb,
                                                   const float* __restrict__ inv,
                                                   unsigned char* __restrict__ m8) {
    __shared__ __align__(16) float m_lds[4][16][68];

    const int w = threadIdx.x >> 6;
    const int l = threadIdx.x & 63;
    const int task = blockIdx.x * 4 + w;     // 0..16383
    const int s = task >> 6;                 // row strip 0..255
    const int c = task & 63;                 // col tile  0..63

    const int fr = l & 15;
    const int fk = (l >> 4) * 8;
    const int g  = l >> 4;
    const int rr = g * 4;
    const int r0 = s * 16;
    const int c0 = c * 64;

    bf16x8 a[4];
    #pragma unroll
    for (int kk = 0; kk < 4; ++kk)
        a[kk] = *reinterpret_cast<const bf16x8*>(
            lb + (size_t)(r0 + fr) * L_K + kk * 32 + fk);

    f32x4 acc[4] = {};
    #pragma unroll
    for (int kk = 0; kk < 4; ++kk) {
        #pragma unroll
        for (int ct = 0; ct < 4; ++ct) {
            const bf16x8 b = *reinterpret_cast<const bf16x8*>(
                lb + (size_t)(c0 + ct * 16 + fr) * L_K + kk * 32 + fk);
            acc[ct] = __builtin_amdgcn_mfma_f32_16x16x32_bf16(a[kk], b, acc[ct], 0, 0, 0);
        }
    }

    float invi[4];
    #pragma unroll
    for (int r = 0; r < 4; ++r) invi[r] = inv[r0 + rr + r];
    float invj[4];
    #pragma unroll
    for (int ct = 0; ct < 4; ++ct) invj[ct] = inv[c0 + ct * 16 + fr];

    // C/D layout (verified): col = ct*16 + (lane&15), row = rr + reg
    #pragma unroll
    for (int ct = 0; ct < 4; ++ct) {
        #pragma unroll
        for (int r = 0; r < 4; ++r) {
            m_lds[w][rr + r][ct * 16 + fr] =
                floorf((acc[ct][r] + 128.0f) * invi[r] * invj[ct]);
        }
    }

    // same-wave LDS write->read: wave-synchronous, no barrier needed
    #pragma unroll
    for (int v = 0; v < 4; ++v) {
        const f32x4 mm = *reinterpret_cast<const f32x4*>(&m_lds[w][4 * v + g][fr * 4]);
        const unsigned int pk = ((unsigned int)(mm[0] + 1.0f)) |
                                ((unsigned int)(mm[1] + 1.0f) << 8) |
                                ((unsigned int)(mm[2] + 1.0f) << 16) |
                                ((unsigned int)(mm[3] + 1.0f) << 24);
        const size_t boff = (size_t)(r0 + 4 * v + g) * B_N + (size_t)(c0 + fr * 4);
        *reinterpret_cast<unsigned int*>(m8 + boff) = pk;
    }
}

// ---------------------------------------------------------------------------
// B: pure streaming smooth-L1 reduce (textbook BW pattern, m13-verified).
// 2048 blocks x 256 thr = 8192 waves = exact chip residency. Each thread:
// exactly 8 iters of {o0 float4, o1 float4, m uchar4}, fully coalesced,
// no bounds checks. loss = 0.5*min(d,1)^2 + max(d,1) - 1, "-1" folded as
// exactly 64 elements PER LANE (8 iters x 8 elems) -- per-lane subtract.
// ---------------------------------------------------------------------------
__global__ __launch_bounds__(256) void loss_kernel(const float* __restrict__ o0,
                                                   const float* __restrict__ o1,
                                                   const unsigned char* __restrict__ m8,
                                                   float* __restrict__ partials) {
    __shared__ float wsum[4];
    const int tid = blockIdx.x * 256 + threadIdx.x;

    float sumA = 0.0f, sumB = 0.0f;
    #pragma unroll
    for (int k = 0; k < 8; ++k) {
        const size_t q = (size_t)tid + (size_t)k * LOSS_THREADS;   // quad index
        const f32x4 p0 = *reinterpret_cast<const f32x4*>(o0 + q * 4);
        const f32x4 p1 = *reinterpret_cast<const f32x4*>(o1 + q * 4);
        const uchar4 mu = *reinterpret_cast<const uchar4*>(m8 + q * 4);

        const float mf[4] = {(float)mu.x - 1.0f, (float)mu.y - 1.0f,
                             (float)mu.z - 1.0f, (float)mu.w - 1.0f};
        #pragma unroll
        for (int j = 0; j < 4; ++j) {
            const float d0 = fabsf(p0[j] - mf[j]);
            const float d1 = fabsf(p1[j] - mf[j]);
            const float u0 = fminf(d0, 1.0f), v0 = fmaxf(d0, 1.0f);
            const float u1 = fminf(d1, 1.0f), v1 = fmaxf(d1, 1.0f);
            sumA = fmaf(u0, u0, sumA);
            sumA = fmaf(u1, u1, sumA);
            sumB += v0 + v1;
        }
    }

    float lsum = 0.5f * sumA + sumB - 64.0f;   // 64 elems per LANE exactly
    #pragma unroll
    for (int m = 32; m >= 1; m >>= 1) lsum += __shfl_xor(lsum, m);

    const int w = threadIdx.x >> 6, l = threadIdx.x & 63;
    if (l == 0) wsum[w] = lsum;
    __syncthreads();
    if (threadIdx.x == 0)
        partials[blockIdx.x] = wsum[0] + wsum[1] + wsum[2] + wsum[3];
}

// ---------------------------------------------------------------------------
// finalize: one block, reduce 2048 partials in double, scale
// ---------------------------------------------------------------------------
__global__ __launch_bounds__(1024) void fin_kernel(const float* __restrict__ partials,
                                                   float* __restrict__ out) {
    __shared__ double wred[16];
    double s = 0.0;
    for (int i = threadIdx.x; i < LOSS_BLOCKS; i += 1024) s += (double)partials[i];
    #pragma unroll
    for (int m = 32; m >= 1; m >>= 1) s += __shfl_xor(s, m);
    const int l = threadIdx.x & 63, w = threadIdx.x >> 6;
    if (l == 0) wred[w] = s;
    __syncthreads();
    if (threadIdx.x == 0) {
        double t = 0.0;
        #pragma unroll
        for (int i = 0; i < 16; ++i) t += wred[i];
        out[0] = (float)(t / (2.0 * (double)B_N * (double)B_N));
    }
}

extern "C" void kernel_launch(void* const* d_in, const int* in_sizes, int n_in,
                              void* d_out, int out_size, void* d_ws, size_t ws_size,
                              hipStream_t stream) {
    const float* o0     = (const float*)d_in[0];
    const float* o1     = (const float*)d_in[1];
    const float* labels = (const float*)d_in[2];
    float* out = (float*)d_out;

    char* ws = (char*)d_ws;
    const size_t MB = 1048576;  // 1 << 20, kept as a plain constant
    unsigned short* lb = (unsigned short*)ws;                   // 1 MB bf16 labels
    float* inv         = (float*)(ws + MB);                     // 16 KB at +1 MB
    float* partials    = (float*)(ws + MB + 16384);             // 8 KB
    unsigned char* m8  = (unsigned char*)(ws + 2 * MB);         // 16 MB at +2 MB

    prep_kernel<<<B_N / 4, 256, 0, stream>>>(labels, lb, inv);
    gram_kernel<<<NTASK / 4, 256, 0, stream>>>(lb, inv, m8);
    loss_kernel<<<LOSS_BLOCKS, 256, 0, stream>>>(o0, o1, m8, partials);
    fin_kernel<<<1, 1024, 0, stream>>>(partials, out);
}